// Round 12
// baseline (400.141 us; speedup 1.0000x reference)
//
#include <hip/hip_runtime.h>
#include <hip/hip_bf16.h>
#include <math.h>

#define NN 4
#define CC 1024
#define DD 768
#define HH 12
#define EE 32
#define MM 4
#define PP 256
#define EMBD 768
#define BSZ 64
#define NCLS 97
#define NP (NN*PP)      // 1024
#define K2D (2*DD)      // 1536
#define OFFS 1

typedef __attribute__((ext_vector_type(4))) float f32x4;
typedef __attribute__((ext_vector_type(4))) int   i32x4;
typedef __attribute__((ext_vector_type(8))) __bf16 bf16x8;

union U8 { bf16x8 bv; i32x4 iv; unsigned u[4]; };

__device__ __forceinline__ unsigned short f2bfu(float x) {
  __hip_bfloat16 h = __float2bfloat16(x);
  unsigned short s;
  __builtin_memcpy(&s, &h, 2);
  return s;
}
__device__ __forceinline__ float bfu2f(unsigned short s) {
  return __uint_as_float(((unsigned)s) << 16);
}

__device__ __forceinline__ float blockReduceSum(float v) {
  #pragma unroll
  for (int off = 32; off > 0; off >>= 1) v += __shfl_down(v, off, 64);
  __shared__ float red_s[8];
  int wid = threadIdx.x >> 6, lane = threadIdx.x & 63;
  int nw = (blockDim.x + 63) >> 6;
  if (lane == 0) red_s[wid] = v;
  __syncthreads();
  if (threadIdx.x == 0) {
    float s = 0.f;
    for (int i = 0; i < nw; ++i) s += red_s[i];
    red_s[0] = s;
  }
  __syncthreads();
  float r = red_s[0];
  __syncthreads();
  return r;
}

// K1: e_emb (logsumexp over valid mentions) + cnt + valid bitmask
__global__ __launch_bounds__(256) void k_entity(const float* __restrict__ seq,
                                                const int* __restrict__ midx,
                                                const unsigned char* __restrict__ mask,
                                                float* __restrict__ e_emb,
                                                float* __restrict__ cntv,
                                                int* __restrict__ vbuf) {
  int ne = blockIdx.x;
  int n = ne / EE;
  __shared__ int pos_s[MM];
  __shared__ int val_s[MM];
  if (threadIdx.x == 0) {
    const int* wm = (const int*)mask;
    int allodd = 1;
    for (int i = 0; i < NN * EE; ++i) {
      if ((wm[i] & 1) == 0) { allodd = 0; break; }
    }
    int vb = 0, cnt = 0;
    for (int m = 0; m < MM; ++m) {
      int idx = midx[ne * MM + m];
      int p = idx + OFFS; if (p > CC - 1) p = CC - 1;
      pos_s[m] = p;
      int v = allodd ? (mask[ne * MM + m] != 0) : (wm[ne * MM + m] != 0);
      val_s[m] = v;
      if (v) { vb |= (1 << m); cnt++; }
    }
    cntv[ne] = (float)cnt;
    vbuf[ne] = vb;
  }
  __syncthreads();
  const float* sb = seq + (size_t)n * CC * DD;
  for (int d = threadIdx.x; d < DD; d += 256) {
    float x[MM];
    float mx = -1e30f;
    #pragma unroll
    for (int m = 0; m < MM; ++m) {
      x[m] = val_s[m] ? sb[(size_t)pos_s[m] * DD + d] : 0.f;
      if (val_s[m]) mx = fmaxf(mx, x[m]);
    }
    float s = 0.f;
    #pragma unroll
    for (int m = 0; m < MM; ++m) {
      if (val_s[m]) s += expf(x[m] - mx);
    }
    e_emb[(size_t)ne * DD + d] = mx + logf(s);
  }
}

// K2: e_att[n][e][h][c] = (1/cnt) * sum_valid att[n,h,pos,c]
__global__ __launch_bounds__(256) void k_eatt(const float* __restrict__ att,
                                              const int* __restrict__ midx,
                                              const float* __restrict__ cntv,
                                              const int* __restrict__ vbuf,
                                              float* __restrict__ e_att) {
  int b = blockIdx.x;
  int n = b / (EE * HH);
  int rem = b % (EE * HH);
  int e = rem / HH, h = rem % HH;
  int ne = n * EE + e;
  __shared__ int pos_s[MM];
  __shared__ int nv_s;
  __shared__ float inv_s;
  if (threadIdx.x == 0) {
    int vb = vbuf[ne];
    int cp = 0;
    for (int m = 0; m < MM; ++m) {
      if (vb & (1 << m)) {
        int p = midx[ne * MM + m] + OFFS; if (p > CC - 1) p = CC - 1;
        pos_s[cp++] = p;
      }
    }
    nv_s = cp;
    inv_s = 1.f / cntv[ne];
  }
  __syncthreads();
  const float* ab = att + ((size_t)n * HH + h) * CC * CC;
  float* ob = e_att + ((size_t)ne * HH + h) * CC;
  int nv = nv_s;
  float inv = inv_s;
  for (int c = threadIdx.x; c < CC; c += 256) {
    float s = 0.f;
    for (int m = 0; m < nv; ++m) s += ab[(size_t)pos_s[m] * CC + c];
    ob[c] = s * inv;
  }
}

// K3: ht[n][p][c] = normalize_c( mean_h(h_att * t_att) )
__global__ __launch_bounds__(256) void k_ht(const float* __restrict__ e_att,
                                            const int* __restrict__ pairs,
                                            float* __restrict__ ht) {
  int np = blockIdx.x;
  int n = np >> 8;  // P=256
  int tid = threadIdx.x;
  int ph = pairs[np * 2], pt = pairs[np * 2 + 1];
  const float* ha = e_att + ((size_t)(n * EE + ph)) * HH * CC;
  const float* ta = e_att + ((size_t)(n * EE + pt)) * HH * CC;
  float v[4];
  float lsum = 0.f;
  #pragma unroll
  for (int i = 0; i < 4; ++i) {
    int c = tid + i * 256;
    float s = 0.f;
    #pragma unroll
    for (int h = 0; h < HH; ++h) s += ha[(size_t)h * CC + c] * ta[(size_t)h * CC + c];
    s *= (1.f / HH);
    v[i] = s;
    lsum += s;
  }
  float tot = blockReduceSum(lsum);
  float inv = 1.f / (tot + 1e-5f);
  #pragma unroll
  for (int i = 0; i < 4; ++i) ht[(size_t)np * CC + tid + i * 256] = v[i] * inv;
}

// K4a: fill hs/ts halves of X from e_emb gathers
__global__ __launch_bounds__(256) void k_fill(const float* __restrict__ e_emb,
                                              const int* __restrict__ pairs,
                                              float* __restrict__ xh,
                                              float* __restrict__ xt) {
  int np = blockIdx.x;
  int n = np >> 8;
  int ph = pairs[np * 2], pt = pairs[np * 2 + 1];
  const float* he = e_emb + (size_t)(n * EE + ph) * DD;
  const float* te = e_emb + (size_t)(n * EE + pt) * DD;
  #pragma unroll
  for (int i = 0; i < 3; ++i) {
    int d = threadIdx.x + i * 256;
    xh[(size_t)np * K2D + d] = he[d];
    xt[(size_t)np * K2D + d] = te[d];
  }
}

#define WSTR 72

// K4b: rs = ht @ seq via MFMA. BM=64, BN=64, 4 waves (2x2), wave tile 32x32.
__global__ __launch_bounds__(256, 2) void k_rs_mfma(const float* __restrict__ ht,
                                                    const float* __restrict__ seq,
                                                    float* __restrict__ xh,
                                                    float* __restrict__ xt) {
  __shared__ __align__(16) unsigned short As[64][WSTR];
  __shared__ __align__(16) unsigned short Bs[64][WSTR];   // [o][k]
  const int tid = threadIdx.x;
  const int lane = tid & 63, wid = tid >> 6;
  const int wr = wid >> 1, wc = wid & 1;
  const int l15 = lane & 15, lg = lane >> 4;
  const int n = blockIdx.z;
  const int r0 = blockIdx.x * 64;           // row within doc
  const int o0 = blockIdx.y * 64;           // output col in [0,768)
  const int jp = tid >> 3, ob = tid & 7;
  const float* Ab = ht + ((size_t)n * PP + r0) * CC;
  const float* Bb = seq + (size_t)n * CC * DD;

  f32x4 acc[2][2];
  #pragma unroll
  for (int a = 0; a < 2; ++a)
    #pragma unroll
    for (int b = 0; b < 2; ++b) acc[a][b] = (f32x4){0.f, 0.f, 0.f, 0.f};

  for (int k0 = 0; k0 < CC; k0 += 64) {
    __syncthreads();
    #pragma unroll
    for (int uu = 0; uu < 2; ++uu) {
      int idx = tid + uu * 256;
      int row = idx >> 3, ch = idx & 7;
      const float* ap = Ab + (size_t)row * CC + k0 + ch * 8;
      f32x4 v0 = *(const f32x4*)ap;
      f32x4 v1 = *(const f32x4*)(ap + 4);
      const float* f0 = (const float*)&v0;
      const float* f1 = (const float*)&v1;
      i32x4 hv;
      #pragma unroll
      for (int p = 0; p < 2; ++p)
        hv[p] = (unsigned)f2bfu(f0[2 * p]) | ((unsigned)f2bfu(f0[2 * p + 1]) << 16);
      #pragma unroll
      for (int p = 0; p < 2; ++p)
        hv[2 + p] = (unsigned)f2bfu(f1[2 * p]) | ((unsigned)f2bfu(f1[2 * p + 1]) << 16);
      *(i32x4*)&As[row][ch * 8] = hv;
    }
    #pragma unroll
    for (int u = 0; u < 2; ++u) {
      f32x4 w0 = *(const f32x4*)&Bb[(size_t)(k0 + 2 * jp) * DD + o0 + 4 * (ob + 8 * u)];
      f32x4 w1 = *(const f32x4*)&Bb[(size_t)(k0 + 2 * jp + 1) * DD + o0 + 4 * (ob + 8 * u)];
      const float* f0 = (const float*)&w0;
      const float* f1 = (const float*)&w1;
      #pragma unroll
      for (int c = 0; c < 4; ++c) {
        unsigned pk = (unsigned)f2bfu(f0[c]) | ((unsigned)f2bfu(f1[c]) << 16);
        *(unsigned*)&Bs[4 * (ob + 8 * u) + c][2 * jp] = pk;
      }
    }
    __syncthreads();
    #pragma unroll
    for (int kc = 0; kc < 2; ++kc) {
      U8 bfr[2];
      #pragma unroll
      for (int nt = 0; nt < 2; ++nt)
        bfr[nt].iv = *(const i32x4*)&Bs[wc * 32 + nt * 16 + l15][kc * 32 + lg * 8];
      #pragma unroll
      for (int mt = 0; mt < 2; ++mt) {
        U8 af;
        af.iv = *(const i32x4*)&As[wr * 32 + mt * 16 + l15][kc * 32 + lg * 8];
        #pragma unroll
        for (int nt = 0; nt < 2; ++nt)
          acc[mt][nt] = __builtin_amdgcn_mfma_f32_16x16x32_bf16(af.bv, bfr[nt].bv, acc[mt][nt], 0, 0, 0);
      }
    }
  }
  #pragma unroll
  for (int mt = 0; mt < 2; ++mt)
    #pragma unroll
    for (int v = 0; v < 4; ++v) {
      int np = n * PP + r0 + wr * 32 + mt * 16 + lg * 4 + v;
      #pragma unroll
      for (int nt = 0; nt < 2; ++nt) {
        int col = o0 + wc * 32 + nt * 16 + l15;
        float val = acc[mt][nt][v];
        xh[(size_t)np * K2D + DD + col] = val;
        xt[(size_t)np * K2D + DD + col] = val;
      }
    }
}

// K5 v2: outb = bf16(tanh(A @ W + b)), A fp32 hi/lo-split. BM=64, BN=64,
// 4 waves (2x2), wave tile 32x32. Grid 16x12x2 = 384 blocks.
__global__ __launch_bounds__(256, 2) void k_tanh_mfma(const float* __restrict__ xh,
                                                      const float* __restrict__ xt,
                                                      const float* __restrict__ headW,
                                                      const float* __restrict__ tailW,
                                                      const float* __restrict__ headb,
                                                      const float* __restrict__ tailb,
                                                      unsigned short* __restrict__ hsb,
                                                      unsigned short* __restrict__ tsb) {
  __shared__ __align__(16) unsigned short Ahi[64][WSTR];
  __shared__ __align__(16) unsigned short Alo[64][WSTR];
  __shared__ __align__(16) unsigned short Ws[64][WSTR];    // [o][k]
  const int z = blockIdx.z;
  const float* A = z ? xt : xh;
  const float* W = z ? tailW : headW;
  const float* bias = z ? tailb : headb;
  unsigned short* outb = z ? tsb : hsb;
  const int tid = threadIdx.x;
  const int lane = tid & 63, wid = tid >> 6;
  const int wr = wid >> 1, wc = wid & 1;
  const int l15 = lane & 15, lg = lane >> 4;
  const int r0 = blockIdx.x * 64, o0 = blockIdx.y * 64;
  const int jp = tid >> 3, ob = tid & 7;

  f32x4 acc[2][2];
  #pragma unroll
  for (int a = 0; a < 2; ++a)
    #pragma unroll
    for (int b = 0; b < 2; ++b) acc[a][b] = (f32x4){0.f, 0.f, 0.f, 0.f};

  for (int k0 = 0; k0 < K2D; k0 += 64) {
    __syncthreads();
    // stage A hi/lo (64 rows x 64 k)
    #pragma unroll
    for (int uu = 0; uu < 2; ++uu) {
      int idx = tid + uu * 256;
      int row = idx >> 3, ch = idx & 7;
      const float* ap = A + (size_t)(r0 + row) * K2D + k0 + ch * 8;
      f32x4 v0 = *(const f32x4*)ap;
      f32x4 v1 = *(const f32x4*)(ap + 4);
      const float* fv0 = (const float*)&v0;
      const float* fv1 = (const float*)&v1;
      float fv[8] = {fv0[0], fv0[1], fv0[2], fv0[3], fv1[0], fv1[1], fv1[2], fv1[3]};
      unsigned short h[8], l[8];
      #pragma unroll
      for (int e = 0; e < 8; ++e) {
        h[e] = f2bfu(fv[e]);
        l[e] = f2bfu(fv[e] - bfu2f(h[e]));
      }
      i32x4 hv, lv;
      #pragma unroll
      for (int p = 0; p < 4; ++p) {
        hv[p] = (unsigned)h[2 * p] | ((unsigned)h[2 * p + 1] << 16);
        lv[p] = (unsigned)l[2 * p] | ((unsigned)l[2 * p + 1] << 16);
      }
      *(i32x4*)&Ahi[row][ch * 8] = hv;
      *(i32x4*)&Alo[row][ch * 8] = lv;
    }
    // stage W transposed (64 k x 64 o)
    #pragma unroll
    for (int u = 0; u < 2; ++u) {
      f32x4 w0 = *(const f32x4*)&W[(size_t)(k0 + 2 * jp) * EMBD + o0 + 4 * (ob + 8 * u)];
      f32x4 w1 = *(const f32x4*)&W[(size_t)(k0 + 2 * jp + 1) * EMBD + o0 + 4 * (ob + 8 * u)];
      const float* f0 = (const float*)&w0;
      const float* f1 = (const float*)&w1;
      #pragma unroll
      for (int c = 0; c < 4; ++c) {
        unsigned pk = (unsigned)f2bfu(f0[c]) | ((unsigned)f2bfu(f1[c]) << 16);
        *(unsigned*)&Ws[4 * (ob + 8 * u) + c][2 * jp] = pk;
      }
    }
    __syncthreads();
    #pragma unroll
    for (int kc = 0; kc < 2; ++kc) {
      U8 bfr[2];
      #pragma unroll
      for (int nt = 0; nt < 2; ++nt)
        bfr[nt].iv = *(const i32x4*)&Ws[wc * 32 + nt * 16 + l15][kc * 32 + lg * 8];
      #pragma unroll
      for (int mt = 0; mt < 2; ++mt) {
        U8 ah, al;
        ah.iv = *(const i32x4*)&Ahi[wr * 32 + mt * 16 + l15][kc * 32 + lg * 8];
        al.iv = *(const i32x4*)&Alo[wr * 32 + mt * 16 + l15][kc * 32 + lg * 8];
        #pragma unroll
        for (int nt = 0; nt < 2; ++nt) {
          acc[mt][nt] = __builtin_amdgcn_mfma_f32_16x16x32_bf16(ah.bv, bfr[nt].bv, acc[mt][nt], 0, 0, 0);
          acc[mt][nt] = __builtin_amdgcn_mfma_f32_16x16x32_bf16(al.bv, bfr[nt].bv, acc[mt][nt], 0, 0, 0);
        }
      }
    }
  }
  float bv[2];
  #pragma unroll
  for (int nt = 0; nt < 2; ++nt) bv[nt] = bias[o0 + wc * 32 + nt * 16 + l15];
  #pragma unroll
  for (int mt = 0; mt < 2; ++mt)
    #pragma unroll
    for (int v = 0; v < 4; ++v) {
      int row = r0 + wr * 32 + mt * 16 + lg * 4 + v;
      #pragma unroll
      for (int nt = 0; nt < 2; ++nt) {
        int col = o0 + wc * 32 + nt * 16 + l15;
        outb[(size_t)row * EMBD + col] = f2bfu(tanhf(acc[mt][nt][v] + bv[nt]));
      }
    }
}

// K6pre v3: direct register gather-transpose, NO LDS, NO barriers.
// Wt[grel][i][o][jc]: 16B chunk ch (j = ch*8..+7 lo/hi pairs) at ch^(o&7).
// Thread t owns o = oc*256+t for oc in 0..2; per (o,ch): 8 scalar fp32
// loads (each instruction 256B-coalesced across lanes), pack, one b128
// store. Every bilW element read exactly once. Output byte-identical to v2.
__global__ __launch_bounds__(256) void k_wt(const float* __restrict__ bilW,
                                            unsigned short* __restrict__ wt,
                                            int gbase) {
  const int grel = blockIdx.x >> 6;
  const int i = blockIdx.x & 63;
  const int t = threadIdx.x;
  const size_t krow = (size_t)(gbase + grel) * 4096 + (size_t)i * 64;
  const float* src = bilW + krow * 768;
  const size_t obase = ((size_t)grel * 64 + i) * 768;
  #pragma unroll
  for (int oc = 0; oc < 3; ++oc) {
    const int o = oc * 256 + t;
    const size_t outb = (obase + o) * 64;
    #pragma unroll
    for (int ch = 0; ch < 8; ++ch) {
      float v[8];
      #pragma unroll
      for (int e = 0; e < 8; ++e)
        v[e] = src[(size_t)(ch * 8 + e) * 768 + o];
      i32x4 pk;
      #pragma unroll
      for (int p = 0; p < 4; ++p)
        pk[p] = (unsigned)f2bfu(v[2 * p]) | ((unsigned)f2bfu(v[2 * p + 1]) << 16);
      *(i32x4*)&wt[outb + (size_t)(ch ^ (o & 7)) * 8] = pk;
    }
  }
}

// K6: group bilinear via MFMA v3 (round-9 verified, 116us). BM=128, BN=128,
// 2x2 waves, wave 64x64. W from pre-transposed bf16 Wt (linear staging,
// swizzle pre-baked); A-tile generated cooperatively into LDS (XOR-swizzled);
// all frag reads at LDS bank floor. 1-D grid with XCD-aware decode.
__global__ __launch_bounds__(256, 2) void k_bil_mfma(
    const unsigned short* __restrict__ hsb,
    const unsigned short* __restrict__ tsb,
    const unsigned short* __restrict__ wt,
    float* __restrict__ part,
    int nslice, int gbase) {
  __shared__ __align__(16) unsigned short b1s[128][72];
  __shared__ __align__(16) unsigned short AsF[128 * 64];
  __shared__ __align__(16) unsigned short WsF[128 * 64];
  const int d = blockIdx.x;
  const int xcd = d & 7;
  const int q = d >> 3;
  const int r = q & 7;
  const int sl = q >> 3;
  const int s = xcd + 8 * sl;
  if (s >= nslice) return;
  const int oy = s % 6;
  const int z = s / 6;
  const int g = gbase + z;
  const int r0 = r * 128;
  const int o0 = oy * 128;

  const int t = threadIdx.x;
  const int lane = t & 63, wid = t >> 6;
  const int wr = wid >> 1, wc = wid & 1;
  const int l15 = lane & 15, lg = lane >> 4;
  const int rr = t >> 1, h = t & 1;   // gen mapping: thread owns (row rr, j-half h)

  // stage b1 slab (padded rows) + b2 into registers
  float b2f[32];
  #pragma unroll
  for (int u = 0; u < 4; ++u) {
    i32x4 hv = *(const i32x4*)&hsb[(size_t)(r0 + rr) * EMBD + g * 64 + h * 32 + u * 8];
    *(i32x4*)&b1s[rr][h * 32 + u * 8] = hv;
    i32x4 tv = *(const i32x4*)&tsb[(size_t)(r0 + rr) * EMBD + g * 64 + h * 32 + u * 8];
    const unsigned short* sp = (const unsigned short*)&tv;
    #pragma unroll
    for (int e = 0; e < 8; ++e) b2f[u * 8 + e] = bfu2f(sp[e]);
  }

  f32x4 acc[4][4];
  #pragma unroll
  for (int a = 0; a < 4; ++a)
    #pragma unroll
    for (int b = 0; b < 4; ++b) acc[a][b] = (f32x4){0.f, 0.f, 0.f, 0.f};

  for (int it = 0; it < 64; ++it) {
    __syncthreads();   // previous iteration's frag readers done (+ b1s ready at it=0)
    // W tile loads (bf16, pre-swizzled) -- issue early
    const size_t wbase = ((size_t)(z * 64 + it) * 768 + o0) * 64;
    i32x4 wv[4];
    #pragma unroll
    for (int u = 0; u < 4; ++u)
      wv[u] = *(const i32x4*)&wt[wbase + (size_t)u * 2048 + t * 8];
    // cooperative A-tile generation: As[rr][j] = bf16(b1[rr]*b2[rr][j])
    float b1 = bfu2f(b1s[rr][it]);
    #pragma unroll
    for (int u = 0; u < 4; ++u) {
      i32x4 a;
      #pragma unroll
      for (int p = 0; p < 4; ++p) {
        unsigned lo = f2bfu(b1 * b2f[u * 8 + 2 * p]);
        unsigned hi = f2bfu(b1 * b2f[u * 8 + 2 * p + 1]);
        a[p] = lo | (hi << 16);
      }
      int sc = (h * 4 + u) ^ (rr & 7);
      *(i32x4*)&AsF[rr * 64 + sc * 8] = a;
    }
    // W tile -> LDS, linear (swizzle baked into Wt)
    #pragma unroll
    for (int u = 0; u < 4; ++u)
      *(i32x4*)&WsF[u * 2048 + t * 8] = wv[u];
    __syncthreads();
    // fragments + MFMA
    #pragma unroll
    for (int ks = 0; ks < 2; ++ks) {
      U8 bfrg[4];
      #pragma unroll
      for (int nt = 0; nt < 4; ++nt) {
        int O = wc * 64 + nt * 16 + l15;
        bfrg[nt].iv = *(const i32x4*)&WsF[O * 64 + ((ks * 4 + lg) ^ (O & 7)) * 8];
      }
      #pragma unroll
      for (int mt = 0; mt < 4; ++mt) {
        int R = wr * 64 + mt * 16 + l15;
        U8 af;
        af.iv = *(const i32x4*)&AsF[R * 64 + ((ks * 4 + lg) ^ (R & 7)) * 8];
        #pragma unroll
        for (int nt = 0; nt < 4; ++nt)
          acc[mt][nt] = __builtin_amdgcn_mfma_f32_16x16x32_bf16(af.bv, bfrg[nt].bv, acc[mt][nt], 0, 0, 0);
      }
    }
  }
  float* pb = part + (size_t)g * NP * EMBD;
  #pragma unroll
  for (int mt = 0; mt < 4; ++mt)
    #pragma unroll
    for (int v = 0; v < 4; ++v) {
      int row = r0 + wr * 64 + mt * 16 + lg * 4 + v;
      #pragma unroll
      for (int nt = 0; nt < 4; ++nt) {
        int col = o0 + wc * 64 + nt * 16 + l15;
        pb[(size_t)row * EMBD + col] = acc[mt][nt][v];
      }
    }
}

// K6b: reduce partials + bias -> embv (f32x4 vectorized)
__global__ __launch_bounds__(256) void k_bred(const float* __restrict__ part,
                                              const float* __restrict__ bilb,
                                              float* __restrict__ embv) {
  int idx4 = (blockIdx.x * 256 + threadIdx.x) * 4;
  int o = idx4 - (idx4 / EMBD) * EMBD;
  f32x4 s = *(const f32x4*)&bilb[o];
  #pragma unroll
  for (int zz = 0; zz < 12; ++zz) {
    f32x4 p = *(const f32x4*)&part[(size_t)zz * NP * EMBD + idx4];
    s = s + p;
  }
  *(f32x4*)&embv[idx4] = s;
}

// K7: rn = l2norm(r_emb_table @ re_W + re_b)
__global__ __launch_bounds__(256) void k_rel(const float* __restrict__ remb,
                                             const float* __restrict__ reW,
                                             const float* __restrict__ reb,
                                             float* __restrict__ rn) {
  int c = blockIdx.x;
  __shared__ float row_s[DD];
  int tid = threadIdx.x;
  for (int d = tid; d < DD; d += 256) row_s[d] = remb[(size_t)c * DD + d];
  __syncthreads();
  float v[3];
  float ss = 0.f;
  #pragma unroll
  for (int i = 0; i < 3; ++i) {
    int j = tid + i * 256;
    float acc = reb[j];
    for (int d = 0; d < DD; ++d) acc += row_s[d] * reW[(size_t)d * EMBD + j];
    v[i] = acc;
    ss += acc * acc;
  }
  float tot = blockReduceSum(ss);
  float scale = 1.f / fmaxf(sqrtf(tot), 1e-12f);
  #pragma unroll
  for (int i = 0; i < 3; ++i) rn[(size_t)c * EMBD + tid + i * 256] = v[i] * scale;
}

// K8: logits[r,c] = l2norm(emb[r]) . rn[c]; wave-parallel class dots.
__global__ __launch_bounds__(128) void k_logits(const float* __restrict__ embv,
                                                const float* __restrict__ rn,
                                                float* __restrict__ out) {
  int r = blockIdx.x;
  __shared__ float row_s[EMBD];
  int tid = threadIdx.x;
  float ss = 0.f;
  #pragma unroll
  for (int i = 0; i < 6; ++i) {
    int d = tid + i * 128;
    float x = embv[(size_t)r * EMBD + d];
    row_s[d] = x;
    ss += x * x;
  }
  float tot = blockReduceSum(ss);
  float inv = 1.f / fmaxf(sqrtf(tot), 1e-12f);
  const int wv = tid >> 6, lane = tid & 63;
  const int gi = lane >> 3, sub = lane & 7;
  for (int pass = 0; pass < 7; ++pass) {
    int c = pass * 16 + wv * 8 + gi;
    float acc = 0.f;
    if (c < NCLS) {
      const float* rp = rn + (size_t)c * EMBD;
      #pragma unroll
      for (int k = 0; k < 96; ++k) acc += row_s[sub + k * 8] * rp[sub + k * 8];
    }
    acc += __shfl_xor(acc, 4, 64);
    acc += __shfl_xor(acc, 2, 64);
    acc += __shfl_xor(acc, 1, 64);
    if (c < NCLS && sub == 0) out[(size_t)r * NCLS + c] = acc * inv;
  }
}

extern "C" void kernel_launch(void* const* d_in, const int* in_sizes, int n_in,
                              void* d_out, int out_size, void* d_ws, size_t ws_size,
                              hipStream_t stream) {
  const float* seq   = (const float*)d_in[0];
  const float* att   = (const float*)d_in[1];
  const int*   midx  = (const int*)d_in[2];
  const unsigned char* mask = (const unsigned char*)d_in[3];
  const int*   pairs = (const int*)d_in[4];
  const float* headW = (const float*)d_in[5];
  const float* headb = (const float*)d_in[6];
  const float* tailW = (const float*)d_in[7];
  const float* tailb = (const float*)d_in[8];
  const float* bilW  = (const float*)d_in[9];
  const float* bilb  = (const float*)d_in[10];
  const float* remb  = (const float*)d_in[11];
  const float* reW   = (const float*)d_in[12];
  const float* reb   = (const float*)d_in[13];
  float* out = (float*)d_out;

  float* w = (float*)d_ws;
  float* e_emb = w;  w += (size_t)NN * EE * DD;
  float* cntv  = w;  w += NN * EE;
  int*   vbuf  = (int*)w; w += NN * EE;
  float* e_att = w;  w += (size_t)NN * EE * HH * CC;     // 6.29 MB
  float* ht    = w;  w += (size_t)NN * PP * CC;          // 4.19 MB
  float* xh    = w;  w += (size_t)NP * K2D;              // 6.29 MB
  float* xt    = w;  w += (size_t)NP * K2D;              // 6.29 MB
  float* embv  = w;  w += (size_t)NP * EMBD;             // 3.15 MB
  float* rn    = w;  w += (size_t)NCLS * EMBD;
  unsigned short* hsb = (unsigned short*)w;              // bf16 [1024][768]
  w += (size_t)NP * EMBD / 2;
  unsigned short* tsb = (unsigned short*)w;
  w += (size_t)NP * EMBD / 2;
  float* part = w;  w += (size_t)12 * NP * EMBD;         // 37.75 MB
  unsigned short* wt_big = (unsigned short*)w;
  size_t wt_bytes = (size_t)12 * 64 * 768 * 64 * 2;      // 75.5 MB
  size_t need_big = (size_t)((char*)wt_big - (char*)d_ws) + wt_bytes;

  k_entity<<<NN * EE, 256, 0, stream>>>(seq, midx, mask, e_emb, cntv, vbuf);
  k_eatt<<<NN * EE * HH, 256, 0, stream>>>(att, midx, cntv, vbuf, e_att);
  k_ht<<<NN * PP, 256, 0, stream>>>(e_att, pairs, ht);
  k_fill<<<NP, 256, 0, stream>>>(e_emb, pairs, xh, xt);
  dim3 g4(PP / 64, DD / 64, NN);
  k_rs_mfma<<<g4, 256, 0, stream>>>(ht, seq, xh, xt);
  dim3 g5(NP / 64, EMBD / 64, 2);
  k_tanh_mfma<<<g5, 256, 0, stream>>>(xh, xt, headW, tailW, headb, tailb, hsb, tsb);

  if (ws_size >= need_big) {
    // single prepass + single bilinear pass (72 slices x 8 row-blocks)
    k_wt<<<12 * 64, 256, 0, stream>>>(bilW, wt_big, 0);
    k_bil_mfma<<<64 * 9, 256, 0, stream>>>(hsb, tsb, wt_big, part, 72, 0);
  } else {
    // 3 rounds of 4 groups; Wt (25.2 MB) aliases dead e_att..embv (26.2 MB)
    unsigned short* wt_small = (unsigned short*)e_att;
    for (int qr = 0; qr < 3; ++qr) {
      k_wt<<<4 * 64, 256, 0, stream>>>(bilW, wt_small, qr * 4);
      k_bil_mfma<<<64 * 3, 256, 0, stream>>>(hsb, tsb, wt_small, part, 24, qr * 4);
    }
  }
  k_bred<<<(NP * EMBD) / 1024, 256, 0, stream>>>(part, bilb, embv);
  k_rel<<<NCLS, 256, 0, stream>>>(remb, reW, reb, rn);
  k_logits<<<NP, 128, 0, stream>>>(embv, rn, out);
}

// Round 13
// 365.032 us; speedup vs baseline: 1.0962x; 1.0962x over previous
//
#include <hip/hip_runtime.h>
#include <hip/hip_bf16.h>
#include <math.h>

#define NN 4
#define CC 1024
#define DD 768
#define HH 12
#define EE 32
#define MM 4
#define PP 256
#define EMBD 768
#define BSZ 64
#define NCLS 97
#define NP (NN*PP)      // 1024
#define K2D (2*DD)      // 1536
#define OFFS 1

typedef __attribute__((ext_vector_type(4))) float f32x4;
typedef __attribute__((ext_vector_type(4))) int   i32x4;
typedef __attribute__((ext_vector_type(8))) __bf16 bf16x8;

union U8 { bf16x8 bv; i32x4 iv; unsigned u[4]; };

__device__ __forceinline__ unsigned short f2bfu(float x) {
  __hip_bfloat16 h = __float2bfloat16(x);
  unsigned short s;
  __builtin_memcpy(&s, &h, 2);
  return s;
}
__device__ __forceinline__ float bfu2f(unsigned short s) {
  return __uint_as_float(((unsigned)s) << 16);
}

__device__ __forceinline__ float blockReduceSum(float v) {
  #pragma unroll
  for (int off = 32; off > 0; off >>= 1) v += __shfl_down(v, off, 64);
  __shared__ float red_s[8];
  int wid = threadIdx.x >> 6, lane = threadIdx.x & 63;
  int nw = (blockDim.x + 63) >> 6;
  if (lane == 0) red_s[wid] = v;
  __syncthreads();
  if (threadIdx.x == 0) {
    float s = 0.f;
    for (int i = 0; i < nw; ++i) s += red_s[i];
    red_s[0] = s;
  }
  __syncthreads();
  float r = red_s[0];
  __syncthreads();
  return r;
}

// K1: e_emb (logsumexp over valid mentions) + cnt + valid bitmask
__global__ __launch_bounds__(256) void k_entity(const float* __restrict__ seq,
                                                const int* __restrict__ midx,
                                                const unsigned char* __restrict__ mask,
                                                float* __restrict__ e_emb,
                                                float* __restrict__ cntv,
                                                int* __restrict__ vbuf) {
  int ne = blockIdx.x;
  int n = ne / EE;
  __shared__ int pos_s[MM];
  __shared__ int val_s[MM];
  if (threadIdx.x == 0) {
    const int* wm = (const int*)mask;
    int allodd = 1;
    for (int i = 0; i < NN * EE; ++i) {
      if ((wm[i] & 1) == 0) { allodd = 0; break; }
    }
    int vb = 0, cnt = 0;
    for (int m = 0; m < MM; ++m) {
      int idx = midx[ne * MM + m];
      int p = idx + OFFS; if (p > CC - 1) p = CC - 1;
      pos_s[m] = p;
      int v = allodd ? (mask[ne * MM + m] != 0) : (wm[ne * MM + m] != 0);
      val_s[m] = v;
      if (v) { vb |= (1 << m); cnt++; }
    }
    cntv[ne] = (float)cnt;
    vbuf[ne] = vb;
  }
  __syncthreads();
  const float* sb = seq + (size_t)n * CC * DD;
  for (int d = threadIdx.x; d < DD; d += 256) {
    float x[MM];
    float mx = -1e30f;
    #pragma unroll
    for (int m = 0; m < MM; ++m) {
      x[m] = val_s[m] ? sb[(size_t)pos_s[m] * DD + d] : 0.f;
      if (val_s[m]) mx = fmaxf(mx, x[m]);
    }
    float s = 0.f;
    #pragma unroll
    for (int m = 0; m < MM; ++m) {
      if (val_s[m]) s += expf(x[m] - mx);
    }
    e_emb[(size_t)ne * DD + d] = mx + logf(s);
  }
}

// K2: e_att[n][e][h][c] = (1/cnt) * sum_valid att[n,h,pos,c]
__global__ __launch_bounds__(256) void k_eatt(const float* __restrict__ att,
                                              const int* __restrict__ midx,
                                              const float* __restrict__ cntv,
                                              const int* __restrict__ vbuf,
                                              float* __restrict__ e_att) {
  int b = blockIdx.x;
  int n = b / (EE * HH);
  int rem = b % (EE * HH);
  int e = rem / HH, h = rem % HH;
  int ne = n * EE + e;
  __shared__ int pos_s[MM];
  __shared__ int nv_s;
  __shared__ float inv_s;
  if (threadIdx.x == 0) {
    int vb = vbuf[ne];
    int cp = 0;
    for (int m = 0; m < MM; ++m) {
      if (vb & (1 << m)) {
        int p = midx[ne * MM + m] + OFFS; if (p > CC - 1) p = CC - 1;
        pos_s[cp++] = p;
      }
    }
    nv_s = cp;
    inv_s = 1.f / cntv[ne];
  }
  __syncthreads();
  const float* ab = att + ((size_t)n * HH + h) * CC * CC;
  float* ob = e_att + ((size_t)ne * HH + h) * CC;
  int nv = nv_s;
  float inv = inv_s;
  for (int c = threadIdx.x; c < CC; c += 256) {
    float s = 0.f;
    for (int m = 0; m < nv; ++m) s += ab[(size_t)pos_s[m] * CC + c];
    ob[c] = s * inv;
  }
}

// K3: ht[n][p][c] = normalize_c( mean_h(h_att * t_att) )
__global__ __launch_bounds__(256) void k_ht(const float* __restrict__ e_att,
                                            const int* __restrict__ pairs,
                                            float* __restrict__ ht) {
  int np = blockIdx.x;
  int n = np >> 8;  // P=256
  int tid = threadIdx.x;
  int ph = pairs[np * 2], pt = pairs[np * 2 + 1];
  const float* ha = e_att + ((size_t)(n * EE + ph)) * HH * CC;
  const float* ta = e_att + ((size_t)(n * EE + pt)) * HH * CC;
  float v[4];
  float lsum = 0.f;
  #pragma unroll
  for (int i = 0; i < 4; ++i) {
    int c = tid + i * 256;
    float s = 0.f;
    #pragma unroll
    for (int h = 0; h < HH; ++h) s += ha[(size_t)h * CC + c] * ta[(size_t)h * CC + c];
    s *= (1.f / HH);
    v[i] = s;
    lsum += s;
  }
  float tot = blockReduceSum(lsum);
  float inv = 1.f / (tot + 1e-5f);
  #pragma unroll
  for (int i = 0; i < 4; ++i) ht[(size_t)np * CC + tid + i * 256] = v[i] * inv;
}

// K4a: fill hs/ts halves of X from e_emb gathers
__global__ __launch_bounds__(256) void k_fill(const float* __restrict__ e_emb,
                                              const int* __restrict__ pairs,
                                              float* __restrict__ xh,
                                              float* __restrict__ xt) {
  int np = blockIdx.x;
  int n = np >> 8;
  int ph = pairs[np * 2], pt = pairs[np * 2 + 1];
  const float* he = e_emb + (size_t)(n * EE + ph) * DD;
  const float* te = e_emb + (size_t)(n * EE + pt) * DD;
  #pragma unroll
  for (int i = 0; i < 3; ++i) {
    int d = threadIdx.x + i * 256;
    xh[(size_t)np * K2D + d] = he[d];
    xt[(size_t)np * K2D + d] = te[d];
  }
}

#define WSTR 72

// K4b: rs = ht @ seq via MFMA. BM=64, BN=64, 4 waves (2x2), wave tile 32x32.
__global__ __launch_bounds__(256, 2) void k_rs_mfma(const float* __restrict__ ht,
                                                    const float* __restrict__ seq,
                                                    float* __restrict__ xh,
                                                    float* __restrict__ xt) {
  __shared__ __align__(16) unsigned short As[64][WSTR];
  __shared__ __align__(16) unsigned short Bs[64][WSTR];   // [o][k]
  const int tid = threadIdx.x;
  const int lane = tid & 63, wid = tid >> 6;
  const int wr = wid >> 1, wc = wid & 1;
  const int l15 = lane & 15, lg = lane >> 4;
  const int n = blockIdx.z;
  const int r0 = blockIdx.x * 64;           // row within doc
  const int o0 = blockIdx.y * 64;           // output col in [0,768)
  const int jp = tid >> 3, ob = tid & 7;
  const float* Ab = ht + ((size_t)n * PP + r0) * CC;
  const float* Bb = seq + (size_t)n * CC * DD;

  f32x4 acc[2][2];
  #pragma unroll
  for (int a = 0; a < 2; ++a)
    #pragma unroll
    for (int b = 0; b < 2; ++b) acc[a][b] = (f32x4){0.f, 0.f, 0.f, 0.f};

  for (int k0 = 0; k0 < CC; k0 += 64) {
    __syncthreads();
    #pragma unroll
    for (int uu = 0; uu < 2; ++uu) {
      int idx = tid + uu * 256;
      int row = idx >> 3, ch = idx & 7;
      const float* ap = Ab + (size_t)row * CC + k0 + ch * 8;
      f32x4 v0 = *(const f32x4*)ap;
      f32x4 v1 = *(const f32x4*)(ap + 4);
      const float* f0 = (const float*)&v0;
      const float* f1 = (const float*)&v1;
      i32x4 hv;
      #pragma unroll
      for (int p = 0; p < 2; ++p)
        hv[p] = (unsigned)f2bfu(f0[2 * p]) | ((unsigned)f2bfu(f0[2 * p + 1]) << 16);
      #pragma unroll
      for (int p = 0; p < 2; ++p)
        hv[2 + p] = (unsigned)f2bfu(f1[2 * p]) | ((unsigned)f2bfu(f1[2 * p + 1]) << 16);
      *(i32x4*)&As[row][ch * 8] = hv;
    }
    #pragma unroll
    for (int u = 0; u < 2; ++u) {
      f32x4 w0 = *(const f32x4*)&Bb[(size_t)(k0 + 2 * jp) * DD + o0 + 4 * (ob + 8 * u)];
      f32x4 w1 = *(const f32x4*)&Bb[(size_t)(k0 + 2 * jp + 1) * DD + o0 + 4 * (ob + 8 * u)];
      const float* f0 = (const float*)&w0;
      const float* f1 = (const float*)&w1;
      #pragma unroll
      for (int c = 0; c < 4; ++c) {
        unsigned pk = (unsigned)f2bfu(f0[c]) | ((unsigned)f2bfu(f1[c]) << 16);
        *(unsigned*)&Bs[4 * (ob + 8 * u) + c][2 * jp] = pk;
      }
    }
    __syncthreads();
    #pragma unroll
    for (int kc = 0; kc < 2; ++kc) {
      U8 bfr[2];
      #pragma unroll
      for (int nt = 0; nt < 2; ++nt)
        bfr[nt].iv = *(const i32x4*)&Bs[wc * 32 + nt * 16 + l15][kc * 32 + lg * 8];
      #pragma unroll
      for (int mt = 0; mt < 2; ++mt) {
        U8 af;
        af.iv = *(const i32x4*)&As[wr * 32 + mt * 16 + l15][kc * 32 + lg * 8];
        #pragma unroll
        for (int nt = 0; nt < 2; ++nt)
          acc[mt][nt] = __builtin_amdgcn_mfma_f32_16x16x32_bf16(af.bv, bfr[nt].bv, acc[mt][nt], 0, 0, 0);
      }
    }
  }
  #pragma unroll
  for (int mt = 0; mt < 2; ++mt)
    #pragma unroll
    for (int v = 0; v < 4; ++v) {
      int np = n * PP + r0 + wr * 32 + mt * 16 + lg * 4 + v;
      #pragma unroll
      for (int nt = 0; nt < 2; ++nt) {
        int col = o0 + wc * 32 + nt * 16 + l15;
        float val = acc[mt][nt][v];
        xh[(size_t)np * K2D + DD + col] = val;
        xt[(size_t)np * K2D + DD + col] = val;
      }
    }
}

// K5 v2: outb = bf16(tanh(A @ W + b)), A fp32 hi/lo-split. BM=64, BN=64,
// 4 waves (2x2), wave tile 32x32. Grid 16x12x2 = 384 blocks.
__global__ __launch_bounds__(256, 2) void k_tanh_mfma(const float* __restrict__ xh,
                                                      const float* __restrict__ xt,
                                                      const float* __restrict__ headW,
                                                      const float* __restrict__ tailW,
                                                      const float* __restrict__ headb,
                                                      const float* __restrict__ tailb,
                                                      unsigned short* __restrict__ hsb,
                                                      unsigned short* __restrict__ tsb) {
  __shared__ __align__(16) unsigned short Ahi[64][WSTR];
  __shared__ __align__(16) unsigned short Alo[64][WSTR];
  __shared__ __align__(16) unsigned short Ws[64][WSTR];    // [o][k]
  const int z = blockIdx.z;
  const float* A = z ? xt : xh;
  const float* W = z ? tailW : headW;
  const float* bias = z ? tailb : headb;
  unsigned short* outb = z ? tsb : hsb;
  const int tid = threadIdx.x;
  const int lane = tid & 63, wid = tid >> 6;
  const int wr = wid >> 1, wc = wid & 1;
  const int l15 = lane & 15, lg = lane >> 4;
  const int r0 = blockIdx.x * 64, o0 = blockIdx.y * 64;
  const int jp = tid >> 3, ob = tid & 7;

  f32x4 acc[2][2];
  #pragma unroll
  for (int a = 0; a < 2; ++a)
    #pragma unroll
    for (int b = 0; b < 2; ++b) acc[a][b] = (f32x4){0.f, 0.f, 0.f, 0.f};

  for (int k0 = 0; k0 < K2D; k0 += 64) {
    __syncthreads();
    // stage A hi/lo (64 rows x 64 k)
    #pragma unroll
    for (int uu = 0; uu < 2; ++uu) {
      int idx = tid + uu * 256;
      int row = idx >> 3, ch = idx & 7;
      const float* ap = A + (size_t)(r0 + row) * K2D + k0 + ch * 8;
      f32x4 v0 = *(const f32x4*)ap;
      f32x4 v1 = *(const f32x4*)(ap + 4);
      const float* fv0 = (const float*)&v0;
      const float* fv1 = (const float*)&v1;
      float fv[8] = {fv0[0], fv0[1], fv0[2], fv0[3], fv1[0], fv1[1], fv1[2], fv1[3]};
      unsigned short h[8], l[8];
      #pragma unroll
      for (int e = 0; e < 8; ++e) {
        h[e] = f2bfu(fv[e]);
        l[e] = f2bfu(fv[e] - bfu2f(h[e]));
      }
      i32x4 hv, lv;
      #pragma unroll
      for (int p = 0; p < 4; ++p) {
        hv[p] = (unsigned)h[2 * p] | ((unsigned)h[2 * p + 1] << 16);
        lv[p] = (unsigned)l[2 * p] | ((unsigned)l[2 * p + 1] << 16);
      }
      *(i32x4*)&Ahi[row][ch * 8] = hv;
      *(i32x4*)&Alo[row][ch * 8] = lv;
    }
    // stage W transposed (64 k x 64 o)
    #pragma unroll
    for (int u = 0; u < 2; ++u) {
      f32x4 w0 = *(const f32x4*)&W[(size_t)(k0 + 2 * jp) * EMBD + o0 + 4 * (ob + 8 * u)];
      f32x4 w1 = *(const f32x4*)&W[(size_t)(k0 + 2 * jp + 1) * EMBD + o0 + 4 * (ob + 8 * u)];
      const float* f0 = (const float*)&w0;
      const float* f1 = (const float*)&w1;
      #pragma unroll
      for (int c = 0; c < 4; ++c) {
        unsigned pk = (unsigned)f2bfu(f0[c]) | ((unsigned)f2bfu(f1[c]) << 16);
        *(unsigned*)&Ws[4 * (ob + 8 * u) + c][2 * jp] = pk;
      }
    }
    __syncthreads();
    #pragma unroll
    for (int kc = 0; kc < 2; ++kc) {
      U8 bfr[2];
      #pragma unroll
      for (int nt = 0; nt < 2; ++nt)
        bfr[nt].iv = *(const i32x4*)&Ws[wc * 32 + nt * 16 + l15][kc * 32 + lg * 8];
      #pragma unroll
      for (int mt = 0; mt < 2; ++mt) {
        U8 ah, al;
        ah.iv = *(const i32x4*)&Ahi[wr * 32 + mt * 16 + l15][kc * 32 + lg * 8];
        al.iv = *(const i32x4*)&Alo[wr * 32 + mt * 16 + l15][kc * 32 + lg * 8];
        #pragma unroll
        for (int nt = 0; nt < 2; ++nt) {
          acc[mt][nt] = __builtin_amdgcn_mfma_f32_16x16x32_bf16(ah.bv, bfr[nt].bv, acc[mt][nt], 0, 0, 0);
          acc[mt][nt] = __builtin_amdgcn_mfma_f32_16x16x32_bf16(al.bv, bfr[nt].bv, acc[mt][nt], 0, 0, 0);
        }
      }
    }
  }
  float bv[2];
  #pragma unroll
  for (int nt = 0; nt < 2; ++nt) bv[nt] = bias[o0 + wc * 32 + nt * 16 + l15];
  #pragma unroll
  for (int mt = 0; mt < 2; ++mt)
    #pragma unroll
    for (int v = 0; v < 4; ++v) {
      int row = r0 + wr * 32 + mt * 16 + lg * 4 + v;
      #pragma unroll
      for (int nt = 0; nt < 2; ++nt) {
        int col = o0 + wc * 32 + nt * 16 + l15;
        outb[(size_t)row * EMBD + col] = f2bfu(tanhf(acc[mt][nt][v] + bv[nt]));
      }
    }
}

// K6pre v4: v2's exact math with oc hoisted to blockIdx.y (grid 768 x 6):
// ONE barrier per block, 6x TLP. Wt[grel][i][o][jc], chunk ch at ch^(o&7),
// output byte-identical to v2. LDS tile [64][128] f32 with chunk^(j&31)
// XOR swizzle (2-way free both sides); writes cover contiguous 128B rows.
__global__ __launch_bounds__(256) void k_wt(const float* __restrict__ bilW,
                                            unsigned short* __restrict__ wt,
                                            int gbase) {
  __shared__ float Ls[64 * 128];
  const int grel = blockIdx.x >> 6;
  const int i = blockIdx.x & 63;
  const int oc = blockIdx.y;
  const int t = threadIdx.x;
  const size_t krow = (size_t)(gbase + grel) * 4096 + (size_t)i * 64;
  const int j4 = t >> 2, qo = t & 3;        // stage mapping
  const int o2 = t >> 1, chb = (t & 1) * 4; // transpose-out mapping
  // stage: rows j4, o-chunks (qo*8+u), XOR-swizzled chunk slots
  #pragma unroll
  for (int u = 0; u < 8; ++u) {
    const int c = qo * 8 + u;
    f32x4 v = *(const f32x4*)&bilW[(krow + j4) * 768 + oc * 128 + c * 4];
    *(f32x4*)&Ls[j4 * 128 + ((c ^ (j4 & 31)) * 4)] = v;
  }
  __syncthreads();
  // transpose out: thread owns (o2, chunks chb..chb+3)
  const int og = oc * 128 + o2;
  const size_t outbase = (((size_t)grel * 64 + i) * 768 + og) * 64;
  #pragma unroll
  for (int u = 0; u < 4; ++u) {
    const int ch = chb + u;
    i32x4 pk;
    #pragma unroll
    for (int p = 0; p < 4; ++p) {
      const int j0 = ch * 8 + 2 * p;
      float v0 = Ls[j0 * 128 + (((o2 >> 2) ^ (j0 & 31)) * 4) + (o2 & 3)];
      const int j1 = j0 + 1;
      float v1 = Ls[j1 * 128 + (((o2 >> 2) ^ (j1 & 31)) * 4) + (o2 & 3)];
      pk[p] = (unsigned)f2bfu(v0) | ((unsigned)f2bfu(v1) << 16);
    }
    *(i32x4*)&wt[outbase + (size_t)(ch ^ (og & 7)) * 8] = pk;
  }
}

// K6: group bilinear via MFMA v3 (round-9 verified, 116us). BM=128, BN=128,
// 2x2 waves, wave 64x64. W from pre-transposed bf16 Wt (linear staging,
// swizzle pre-baked); A-tile generated cooperatively into LDS (XOR-swizzled);
// all frag reads at LDS bank floor. 1-D grid with XCD-aware decode.
__global__ __launch_bounds__(256, 2) void k_bil_mfma(
    const unsigned short* __restrict__ hsb,
    const unsigned short* __restrict__ tsb,
    const unsigned short* __restrict__ wt,
    float* __restrict__ part,
    int nslice, int gbase) {
  __shared__ __align__(16) unsigned short b1s[128][72];
  __shared__ __align__(16) unsigned short AsF[128 * 64];
  __shared__ __align__(16) unsigned short WsF[128 * 64];
  const int d = blockIdx.x;
  const int xcd = d & 7;
  const int q = d >> 3;
  const int r = q & 7;
  const int sl = q >> 3;
  const int s = xcd + 8 * sl;
  if (s >= nslice) return;
  const int oy = s % 6;
  const int z = s / 6;
  const int g = gbase + z;
  const int r0 = r * 128;
  const int o0 = oy * 128;

  const int t = threadIdx.x;
  const int lane = t & 63, wid = t >> 6;
  const int wr = wid >> 1, wc = wid & 1;
  const int l15 = lane & 15, lg = lane >> 4;
  const int rr = t >> 1, h = t & 1;   // gen mapping: thread owns (row rr, j-half h)

  // stage b1 slab (padded rows) + b2 into registers
  float b2f[32];
  #pragma unroll
  for (int u = 0; u < 4; ++u) {
    i32x4 hv = *(const i32x4*)&hsb[(size_t)(r0 + rr) * EMBD + g * 64 + h * 32 + u * 8];
    *(i32x4*)&b1s[rr][h * 32 + u * 8] = hv;
    i32x4 tv = *(const i32x4*)&tsb[(size_t)(r0 + rr) * EMBD + g * 64 + h * 32 + u * 8];
    const unsigned short* sp = (const unsigned short*)&tv;
    #pragma unroll
    for (int e = 0; e < 8; ++e) b2f[u * 8 + e] = bfu2f(sp[e]);
  }

  f32x4 acc[4][4];
  #pragma unroll
  for (int a = 0; a < 4; ++a)
    #pragma unroll
    for (int b = 0; b < 4; ++b) acc[a][b] = (f32x4){0.f, 0.f, 0.f, 0.f};

  for (int it = 0; it < 64; ++it) {
    __syncthreads();   // previous iteration's frag readers done (+ b1s ready at it=0)
    // W tile loads (bf16, pre-swizzled) -- issue early
    const size_t wbase = ((size_t)(z * 64 + it) * 768 + o0) * 64;
    i32x4 wv[4];
    #pragma unroll
    for (int u = 0; u < 4; ++u)
      wv[u] = *(const i32x4*)&wt[wbase + (size_t)u * 2048 + t * 8];
    // cooperative A-tile generation: As[rr][j] = bf16(b1[rr]*b2[rr][j])
    float b1 = bfu2f(b1s[rr][it]);
    #pragma unroll
    for (int u = 0; u < 4; ++u) {
      i32x4 a;
      #pragma unroll
      for (int p = 0; p < 4; ++p) {
        unsigned lo = f2bfu(b1 * b2f[u * 8 + 2 * p]);
        unsigned hi = f2bfu(b1 * b2f[u * 8 + 2 * p + 1]);
        a[p] = lo | (hi << 16);
      }
      int sc = (h * 4 + u) ^ (rr & 7);
      *(i32x4*)&AsF[rr * 64 + sc * 8] = a;
    }
    // W tile -> LDS, linear (swizzle baked into Wt)
    #pragma unroll
    for (int u = 0; u < 4; ++u)
      *(i32x4*)&WsF[u * 2048 + t * 8] = wv[u];
    __syncthreads();
    // fragments + MFMA
    #pragma unroll
    for (int ks = 0; ks < 2; ++ks) {
      U8 bfrg[4];
      #pragma unroll
      for (int nt = 0; nt < 4; ++nt) {
        int O = wc * 64 + nt * 16 + l15;
        bfrg[nt].iv = *(const i32x4*)&WsF[O * 64 + ((ks * 4 + lg) ^ (O & 7)) * 8];
      }
      #pragma unroll
      for (int mt = 0; mt < 4; ++mt) {
        int R = wr * 64 + mt * 16 + l15;
        U8 af;
        af.iv = *(const i32x4*)&AsF[R * 64 + ((ks * 4 + lg) ^ (R & 7)) * 8];
        #pragma unroll
        for (int nt = 0; nt < 4; ++nt)
          acc[mt][nt] = __builtin_amdgcn_mfma_f32_16x16x32_bf16(af.bv, bfrg[nt].bv, acc[mt][nt], 0, 0, 0);
      }
    }
  }
  float* pb = part + (size_t)g * NP * EMBD;
  #pragma unroll
  for (int mt = 0; mt < 4; ++mt)
    #pragma unroll
    for (int v = 0; v < 4; ++v) {
      int row = r0 + wr * 64 + mt * 16 + lg * 4 + v;
      #pragma unroll
      for (int nt = 0; nt < 4; ++nt) {
        int col = o0 + wc * 64 + nt * 16 + l15;
        pb[(size_t)row * EMBD + col] = acc[mt][nt][v];
      }
    }
}

// K6b: reduce partials + bias -> embv (f32x4 vectorized)
__global__ __launch_bounds__(256) void k_bred(const float* __restrict__ part,
                                              const float* __restrict__ bilb,
                                              float* __restrict__ embv) {
  int idx4 = (blockIdx.x * 256 + threadIdx.x) * 4;
  int o = idx4 - (idx4 / EMBD) * EMBD;
  f32x4 s = *(const f32x4*)&bilb[o];
  #pragma unroll
  for (int zz = 0; zz < 12; ++zz) {
    f32x4 p = *(const f32x4*)&part[(size_t)zz * NP * EMBD + idx4];
    s = s + p;
  }
  *(f32x4*)&embv[idx4] = s;
}

// K7: rn = l2norm(r_emb_table @ re_W + re_b)
__global__ __launch_bounds__(256) void k_rel(const float* __restrict__ remb,
                                             const float* __restrict__ reW,
                                             const float* __restrict__ reb,
                                             float* __restrict__ rn) {
  int c = blockIdx.x;
  __shared__ float row_s[DD];
  int tid = threadIdx.x;
  for (int d = tid; d < DD; d += 256) row_s[d] = remb[(size_t)c * DD + d];
  __syncthreads();
  float v[3];
  float ss = 0.f;
  #pragma unroll
  for (int i = 0; i < 3; ++i) {
    int j = tid + i * 256;
    float acc = reb[j];
    for (int d = 0; d < DD; ++d) acc += row_s[d] * reW[(size_t)d * EMBD + j];
    v[i] = acc;
    ss += acc * acc;
  }
  float tot = blockReduceSum(ss);
  float scale = 1.f / fmaxf(sqrtf(tot), 1e-12f);
  #pragma unroll
  for (int i = 0; i < 3; ++i) rn[(size_t)c * EMBD + tid + i * 256] = v[i] * scale;
}

// K8: logits[r,c] = l2norm(emb[r]) . rn[c]; wave-parallel class dots.
__global__ __launch_bounds__(128) void k_logits(const float* __restrict__ embv,
                                                const float* __restrict__ rn,
                                                float* __restrict__ out) {
  int r = blockIdx.x;
  __shared__ float row_s[EMBD];
  int tid = threadIdx.x;
  float ss = 0.f;
  #pragma unroll
  for (int i = 0; i < 6; ++i) {
    int d = tid + i * 128;
    float x = embv[(size_t)r * EMBD + d];
    row_s[d] = x;
    ss += x * x;
  }
  float tot = blockReduceSum(ss);
  float inv = 1.f / fmaxf(sqrtf(tot), 1e-12f);
  const int wv = tid >> 6, lane = tid & 63;
  const int gi = lane >> 3, sub = lane & 7;
  for (int pass = 0; pass < 7; ++pass) {
    int c = pass * 16 + wv * 8 + gi;
    float acc = 0.f;
    if (c < NCLS) {
      const float* rp = rn + (size_t)c * EMBD;
      #pragma unroll
      for (int k = 0; k < 96; ++k) acc += row_s[sub + k * 8] * rp[sub + k * 8];
    }
    acc += __shfl_xor(acc, 4, 64);
    acc += __shfl_xor(acc, 2, 64);
    acc += __shfl_xor(acc, 1, 64);
    if (c < NCLS && sub == 0) out[(size_t)r * NCLS + c] = acc * inv;
  }
}

extern "C" void kernel_launch(void* const* d_in, const int* in_sizes, int n_in,
                              void* d_out, int out_size, void* d_ws, size_t ws_size,
                              hipStream_t stream) {
  const float* seq   = (const float*)d_in[0];
  const float* att   = (const float*)d_in[1];
  const int*   midx  = (const int*)d_in[2];
  const unsigned char* mask = (const unsigned char*)d_in[3];
  const int*   pairs = (const int*)d_in[4];
  const float* headW = (const float*)d_in[5];
  const float* headb = (const float*)d_in[6];
  const float* tailW = (const float*)d_in[7];
  const float* tailb = (const float*)d_in[8];
  const float* bilW  = (const float*)d_in[9];
  const float* bilb  = (const float*)d_in[10];
  const float* remb  = (const float*)d_in[11];
  const float* reW   = (const float*)d_in[12];
  const float* reb   = (const float*)d_in[13];
  float* out = (float*)d_out;

  float* w = (float*)d_ws;
  float* e_emb = w;  w += (size_t)NN * EE * DD;
  float* cntv  = w;  w += NN * EE;
  int*   vbuf  = (int*)w; w += NN * EE;
  float* e_att = w;  w += (size_t)NN * EE * HH * CC;     // 6.29 MB
  float* ht    = w;  w += (size_t)NN * PP * CC;          // 4.19 MB
  float* xh    = w;  w += (size_t)NP * K2D;              // 6.29 MB
  float* xt    = w;  w += (size_t)NP * K2D;              // 6.29 MB
  float* embv  = w;  w += (size_t)NP * EMBD;             // 3.15 MB
  float* rn    = w;  w += (size_t)NCLS * EMBD;
  unsigned short* hsb = (unsigned short*)w;              // bf16 [1024][768]
  w += (size_t)NP * EMBD / 2;
  unsigned short* tsb = (unsigned short*)w;
  w += (size_t)NP * EMBD / 2;
  float* part = w;  w += (size_t)12 * NP * EMBD;         // 37.75 MB
  unsigned short* wt_big = (unsigned short*)w;
  size_t wt_bytes = (size_t)12 * 64 * 768 * 64 * 2;      // 75.5 MB
  size_t need_big = (size_t)((char*)wt_big - (char*)d_ws) + wt_bytes;

  k_entity<<<NN * EE, 256, 0, stream>>>(seq, midx, mask, e_emb, cntv, vbuf);
  k_eatt<<<NN * EE * HH, 256, 0, stream>>>(att, midx, cntv, vbuf, e_att);
  k_ht<<<NN * PP, 256, 0, stream>>>(e_att, pairs, ht);
  k_fill<<<NP, 256, 0, stream>>>(e_emb, pairs, xh, xt);
  dim3 g4(PP / 64, DD / 64, NN);
  k_rs_mfma<<<g4, 256, 0, stream>>>(ht, seq, xh, xt);
  dim3 g5(NP / 64, EMBD / 64, 2);
  k_tanh_mfma<<<g5, 256, 0, stream>>>(xh, xt, headW, tailW, headb, tailb, hsb, tsb);

  if (ws_size >= need_big) {
    // single prepass + single bilinear pass (72 slices x 8 row-blocks)
    dim3 gw(12 * 64, 6);
    k_wt<<<gw, 256, 0, stream>>>(bilW, wt_big, 0);
    k_bil_mfma<<<64 * 9, 256, 0, stream>>>(hsb, tsb, wt_big, part, 72, 0);
  } else {
    // 3 rounds of 4 groups; Wt (25.2 MB) aliases dead e_att..embv (26.2 MB)
    unsigned short* wt_small = (unsigned short*)e_att;
    for (int qr = 0; qr < 3; ++qr) {
      dim3 gw(4 * 64, 6);
      k_wt<<<gw, 256, 0, stream>>>(bilW, wt_small, qr * 4);
      k_bil_mfma<<<64 * 3, 256, 0, stream>>>(hsb, tsb, wt_small, part, 24, qr * 4);
    }
  }
  k_bred<<<(NP * EMBD) / 1024, 256, 0, stream>>>(part, bilb, embv);
  k_rel<<<NCLS, 256, 0, stream>>>(remb, reW, reb, rn);
  k_logits<<<NP, 128, 0, stream>>>(embv, rn, out);
}

// Round 14
// 349.484 us; speedup vs baseline: 1.1449x; 1.0445x over previous
//
#include <hip/hip_runtime.h>
#include <hip/hip_bf16.h>
#include <math.h>

#define NN 4
#define CC 1024
#define DD 768
#define HH 12
#define EE 32
#define MM 4
#define PP 256
#define EMBD 768
#define BSZ 64
#define NCLS 97
#define NP (NN*PP)      // 1024
#define K2D (2*DD)      // 1536
#define OFFS 1

typedef __attribute__((ext_vector_type(4))) float f32x4;
typedef __attribute__((ext_vector_type(4))) int   i32x4;
typedef __attribute__((ext_vector_type(8))) __bf16 bf16x8;

union U8 { bf16x8 bv; i32x4 iv; unsigned u[4]; };

__device__ __forceinline__ unsigned short f2bfu(float x) {
  __hip_bfloat16 h = __float2bfloat16(x);
  unsigned short s;
  __builtin_memcpy(&s, &h, 2);
  return s;
}
__device__ __forceinline__ float bfu2f(unsigned short s) {
  return __uint_as_float(((unsigned)s) << 16);
}

__device__ __forceinline__ float blockReduceSum(float v) {
  #pragma unroll
  for (int off = 32; off > 0; off >>= 1) v += __shfl_down(v, off, 64);
  __shared__ float red_s[8];
  int wid = threadIdx.x >> 6, lane = threadIdx.x & 63;
  int nw = (blockDim.x + 63) >> 6;
  if (lane == 0) red_s[wid] = v;
  __syncthreads();
  if (threadIdx.x == 0) {
    float s = 0.f;
    for (int i = 0; i < nw; ++i) s += red_s[i];
    red_s[0] = s;
  }
  __syncthreads();
  float r = red_s[0];
  __syncthreads();
  return r;
}

// K1: e_emb (logsumexp over valid mentions) + cnt + valid bitmask
__global__ __launch_bounds__(256) void k_entity(const float* __restrict__ seq,
                                                const int* __restrict__ midx,
                                                const unsigned char* __restrict__ mask,
                                                float* __restrict__ e_emb,
                                                float* __restrict__ cntv,
                                                int* __restrict__ vbuf) {
  int ne = blockIdx.x;
  int n = ne / EE;
  __shared__ int pos_s[MM];
  __shared__ int val_s[MM];
  if (threadIdx.x == 0) {
    const int* wm = (const int*)mask;
    int allodd = 1;
    for (int i = 0; i < NN * EE; ++i) {
      if ((wm[i] & 1) == 0) { allodd = 0; break; }
    }
    int vb = 0, cnt = 0;
    for (int m = 0; m < MM; ++m) {
      int idx = midx[ne * MM + m];
      int p = idx + OFFS; if (p > CC - 1) p = CC - 1;
      pos_s[m] = p;
      int v = allodd ? (mask[ne * MM + m] != 0) : (wm[ne * MM + m] != 0);
      val_s[m] = v;
      if (v) { vb |= (1 << m); cnt++; }
    }
    cntv[ne] = (float)cnt;
    vbuf[ne] = vb;
  }
  __syncthreads();
  const float* sb = seq + (size_t)n * CC * DD;
  for (int d = threadIdx.x; d < DD; d += 256) {
    float x[MM];
    float mx = -1e30f;
    #pragma unroll
    for (int m = 0; m < MM; ++m) {
      x[m] = val_s[m] ? sb[(size_t)pos_s[m] * DD + d] : 0.f;
      if (val_s[m]) mx = fmaxf(mx, x[m]);
    }
    float s = 0.f;
    #pragma unroll
    for (int m = 0; m < MM; ++m) {
      if (val_s[m]) s += expf(x[m] - mx);
    }
    e_emb[(size_t)ne * DD + d] = mx + logf(s);
  }
}

// K2: e_att[n][e][h][c] = (1/cnt) * sum_valid att[n,h,pos,c]
__global__ __launch_bounds__(256) void k_eatt(const float* __restrict__ att,
                                              const int* __restrict__ midx,
                                              const float* __restrict__ cntv,
                                              const int* __restrict__ vbuf,
                                              float* __restrict__ e_att) {
  int b = blockIdx.x;
  int n = b / (EE * HH);
  int rem = b % (EE * HH);
  int e = rem / HH, h = rem % HH;
  int ne = n * EE + e;
  __shared__ int pos_s[MM];
  __shared__ int nv_s;
  __shared__ float inv_s;
  if (threadIdx.x == 0) {
    int vb = vbuf[ne];
    int cp = 0;
    for (int m = 0; m < MM; ++m) {
      if (vb & (1 << m)) {
        int p = midx[ne * MM + m] + OFFS; if (p > CC - 1) p = CC - 1;
        pos_s[cp++] = p;
      }
    }
    nv_s = cp;
    inv_s = 1.f / cntv[ne];
  }
  __syncthreads();
  const float* ab = att + ((size_t)n * HH + h) * CC * CC;
  float* ob = e_att + ((size_t)ne * HH + h) * CC;
  int nv = nv_s;
  float inv = inv_s;
  for (int c = threadIdx.x; c < CC; c += 256) {
    float s = 0.f;
    for (int m = 0; m < nv; ++m) s += ab[(size_t)pos_s[m] * CC + c];
    ob[c] = s * inv;
  }
}

// K3: ht[n][p][c] = normalize_c( mean_h(h_att * t_att) )
__global__ __launch_bounds__(256) void k_ht(const float* __restrict__ e_att,
                                            const int* __restrict__ pairs,
                                            float* __restrict__ ht) {
  int np = blockIdx.x;
  int n = np >> 8;  // P=256
  int tid = threadIdx.x;
  int ph = pairs[np * 2], pt = pairs[np * 2 + 1];
  const float* ha = e_att + ((size_t)(n * EE + ph)) * HH * CC;
  const float* ta = e_att + ((size_t)(n * EE + pt)) * HH * CC;
  float v[4];
  float lsum = 0.f;
  #pragma unroll
  for (int i = 0; i < 4; ++i) {
    int c = tid + i * 256;
    float s = 0.f;
    #pragma unroll
    for (int h = 0; h < HH; ++h) s += ha[(size_t)h * CC + c] * ta[(size_t)h * CC + c];
    s *= (1.f / HH);
    v[i] = s;
    lsum += s;
  }
  float tot = blockReduceSum(lsum);
  float inv = 1.f / (tot + 1e-5f);
  #pragma unroll
  for (int i = 0; i < 4; ++i) ht[(size_t)np * CC + tid + i * 256] = v[i] * inv;
}

// K4a: fill hs/ts halves of X from e_emb gathers
__global__ __launch_bounds__(256) void k_fill(const float* __restrict__ e_emb,
                                              const int* __restrict__ pairs,
                                              float* __restrict__ xh,
                                              float* __restrict__ xt) {
  int np = blockIdx.x;
  int n = np >> 8;
  int ph = pairs[np * 2], pt = pairs[np * 2 + 1];
  const float* he = e_emb + (size_t)(n * EE + ph) * DD;
  const float* te = e_emb + (size_t)(n * EE + pt) * DD;
  #pragma unroll
  for (int i = 0; i < 3; ++i) {
    int d = threadIdx.x + i * 256;
    xh[(size_t)np * K2D + d] = he[d];
    xt[(size_t)np * K2D + d] = te[d];
  }
}

#define WSTR 72

// K4b: rs = ht @ seq via MFMA. BM=64, BN=64, 4 waves (2x2), wave tile 32x32.
__global__ __launch_bounds__(256, 2) void k_rs_mfma(const float* __restrict__ ht,
                                                    const float* __restrict__ seq,
                                                    float* __restrict__ xh,
                                                    float* __restrict__ xt) {
  __shared__ __align__(16) unsigned short As[64][WSTR];
  __shared__ __align__(16) unsigned short Bs[64][WSTR];   // [o][k]
  const int tid = threadIdx.x;
  const int lane = tid & 63, wid = tid >> 6;
  const int wr = wid >> 1, wc = wid & 1;
  const int l15 = lane & 15, lg = lane >> 4;
  const int n = blockIdx.z;
  const int r0 = blockIdx.x * 64;           // row within doc
  const int o0 = blockIdx.y * 64;           // output col in [0,768)
  const int jp = tid >> 3, ob = tid & 7;
  const float* Ab = ht + ((size_t)n * PP + r0) * CC;
  const float* Bb = seq + (size_t)n * CC * DD;

  f32x4 acc[2][2];
  #pragma unroll
  for (int a = 0; a < 2; ++a)
    #pragma unroll
    for (int b = 0; b < 2; ++b) acc[a][b] = (f32x4){0.f, 0.f, 0.f, 0.f};

  for (int k0 = 0; k0 < CC; k0 += 64) {
    __syncthreads();
    #pragma unroll
    for (int uu = 0; uu < 2; ++uu) {
      int idx = tid + uu * 256;
      int row = idx >> 3, ch = idx & 7;
      const float* ap = Ab + (size_t)row * CC + k0 + ch * 8;
      f32x4 v0 = *(const f32x4*)ap;
      f32x4 v1 = *(const f32x4*)(ap + 4);
      const float* f0 = (const float*)&v0;
      const float* f1 = (const float*)&v1;
      i32x4 hv;
      #pragma unroll
      for (int p = 0; p < 2; ++p)
        hv[p] = (unsigned)f2bfu(f0[2 * p]) | ((unsigned)f2bfu(f0[2 * p + 1]) << 16);
      #pragma unroll
      for (int p = 0; p < 2; ++p)
        hv[2 + p] = (unsigned)f2bfu(f1[2 * p]) | ((unsigned)f2bfu(f1[2 * p + 1]) << 16);
      *(i32x4*)&As[row][ch * 8] = hv;
    }
    #pragma unroll
    for (int u = 0; u < 2; ++u) {
      f32x4 w0 = *(const f32x4*)&Bb[(size_t)(k0 + 2 * jp) * DD + o0 + 4 * (ob + 8 * u)];
      f32x4 w1 = *(const f32x4*)&Bb[(size_t)(k0 + 2 * jp + 1) * DD + o0 + 4 * (ob + 8 * u)];
      const float* f0 = (const float*)&w0;
      const float* f1 = (const float*)&w1;
      #pragma unroll
      for (int c = 0; c < 4; ++c) {
        unsigned pk = (unsigned)f2bfu(f0[c]) | ((unsigned)f2bfu(f1[c]) << 16);
        *(unsigned*)&Bs[4 * (ob + 8 * u) + c][2 * jp] = pk;
      }
    }
    __syncthreads();
    #pragma unroll
    for (int kc = 0; kc < 2; ++kc) {
      U8 bfr[2];
      #pragma unroll
      for (int nt = 0; nt < 2; ++nt)
        bfr[nt].iv = *(const i32x4*)&Bs[wc * 32 + nt * 16 + l15][kc * 32 + lg * 8];
      #pragma unroll
      for (int mt = 0; mt < 2; ++mt) {
        U8 af;
        af.iv = *(const i32x4*)&As[wr * 32 + mt * 16 + l15][kc * 32 + lg * 8];
        #pragma unroll
        for (int nt = 0; nt < 2; ++nt)
          acc[mt][nt] = __builtin_amdgcn_mfma_f32_16x16x32_bf16(af.bv, bfr[nt].bv, acc[mt][nt], 0, 0, 0);
      }
    }
  }
  #pragma unroll
  for (int mt = 0; mt < 2; ++mt)
    #pragma unroll
    for (int v = 0; v < 4; ++v) {
      int np = n * PP + r0 + wr * 32 + mt * 16 + lg * 4 + v;
      #pragma unroll
      for (int nt = 0; nt < 2; ++nt) {
        int col = o0 + wc * 32 + nt * 16 + l15;
        float val = acc[mt][nt][v];
        xh[(size_t)np * K2D + DD + col] = val;
        xt[(size_t)np * K2D + DD + col] = val;
      }
    }
}

// K5 v2: outb = bf16(tanh(A @ W + b)), A fp32 hi/lo-split. BM=64, BN=64,
// 4 waves (2x2), wave tile 32x32. Grid 16x12x2 = 384 blocks.
__global__ __launch_bounds__(256, 2) void k_tanh_mfma(const float* __restrict__ xh,
                                                      const float* __restrict__ xt,
                                                      const float* __restrict__ headW,
                                                      const float* __restrict__ tailW,
                                                      const float* __restrict__ headb,
                                                      const float* __restrict__ tailb,
                                                      unsigned short* __restrict__ hsb,
                                                      unsigned short* __restrict__ tsb) {
  __shared__ __align__(16) unsigned short Ahi[64][WSTR];
  __shared__ __align__(16) unsigned short Alo[64][WSTR];
  __shared__ __align__(16) unsigned short Ws[64][WSTR];    // [o][k]
  const int z = blockIdx.z;
  const float* A = z ? xt : xh;
  const float* W = z ? tailW : headW;
  const float* bias = z ? tailb : headb;
  unsigned short* outb = z ? tsb : hsb;
  const int tid = threadIdx.x;
  const int lane = tid & 63, wid = tid >> 6;
  const int wr = wid >> 1, wc = wid & 1;
  const int l15 = lane & 15, lg = lane >> 4;
  const int r0 = blockIdx.x * 64, o0 = blockIdx.y * 64;
  const int jp = tid >> 3, ob = tid & 7;

  f32x4 acc[2][2];
  #pragma unroll
  for (int a = 0; a < 2; ++a)
    #pragma unroll
    for (int b = 0; b < 2; ++b) acc[a][b] = (f32x4){0.f, 0.f, 0.f, 0.f};

  for (int k0 = 0; k0 < K2D; k0 += 64) {
    __syncthreads();
    // stage A hi/lo (64 rows x 64 k)
    #pragma unroll
    for (int uu = 0; uu < 2; ++uu) {
      int idx = tid + uu * 256;
      int row = idx >> 3, ch = idx & 7;
      const float* ap = A + (size_t)(r0 + row) * K2D + k0 + ch * 8;
      f32x4 v0 = *(const f32x4*)ap;
      f32x4 v1 = *(const f32x4*)(ap + 4);
      const float* fv0 = (const float*)&v0;
      const float* fv1 = (const float*)&v1;
      float fv[8] = {fv0[0], fv0[1], fv0[2], fv0[3], fv1[0], fv1[1], fv1[2], fv1[3]};
      unsigned short h[8], l[8];
      #pragma unroll
      for (int e = 0; e < 8; ++e) {
        h[e] = f2bfu(fv[e]);
        l[e] = f2bfu(fv[e] - bfu2f(h[e]));
      }
      i32x4 hv, lv;
      #pragma unroll
      for (int p = 0; p < 4; ++p) {
        hv[p] = (unsigned)h[2 * p] | ((unsigned)h[2 * p + 1] << 16);
        lv[p] = (unsigned)l[2 * p] | ((unsigned)l[2 * p + 1] << 16);
      }
      *(i32x4*)&Ahi[row][ch * 8] = hv;
      *(i32x4*)&Alo[row][ch * 8] = lv;
    }
    // stage W transposed (64 k x 64 o)
    #pragma unroll
    for (int u = 0; u < 2; ++u) {
      f32x4 w0 = *(const f32x4*)&W[(size_t)(k0 + 2 * jp) * EMBD + o0 + 4 * (ob + 8 * u)];
      f32x4 w1 = *(const f32x4*)&W[(size_t)(k0 + 2 * jp + 1) * EMBD + o0 + 4 * (ob + 8 * u)];
      const float* f0 = (const float*)&w0;
      const float* f1 = (const float*)&w1;
      #pragma unroll
      for (int c = 0; c < 4; ++c) {
        unsigned pk = (unsigned)f2bfu(f0[c]) | ((unsigned)f2bfu(f1[c]) << 16);
        *(unsigned*)&Ws[4 * (ob + 8 * u) + c][2 * jp] = pk;
      }
    }
    __syncthreads();
    #pragma unroll
    for (int kc = 0; kc < 2; ++kc) {
      U8 bfr[2];
      #pragma unroll
      for (int nt = 0; nt < 2; ++nt)
        bfr[nt].iv = *(const i32x4*)&Ws[wc * 32 + nt * 16 + l15][kc * 32 + lg * 8];
      #pragma unroll
      for (int mt = 0; mt < 2; ++mt) {
        U8 ah, al;
        ah.iv = *(const i32x4*)&Ahi[wr * 32 + mt * 16 + l15][kc * 32 + lg * 8];
        al.iv = *(const i32x4*)&Alo[wr * 32 + mt * 16 + l15][kc * 32 + lg * 8];
        #pragma unroll
        for (int nt = 0; nt < 2; ++nt) {
          acc[mt][nt] = __builtin_amdgcn_mfma_f32_16x16x32_bf16(ah.bv, bfr[nt].bv, acc[mt][nt], 0, 0, 0);
          acc[mt][nt] = __builtin_amdgcn_mfma_f32_16x16x32_bf16(al.bv, bfr[nt].bv, acc[mt][nt], 0, 0, 0);
        }
      }
    }
  }
  float bv[2];
  #pragma unroll
  for (int nt = 0; nt < 2; ++nt) bv[nt] = bias[o0 + wc * 32 + nt * 16 + l15];
  #pragma unroll
  for (int mt = 0; mt < 2; ++mt)
    #pragma unroll
    for (int v = 0; v < 4; ++v) {
      int row = r0 + wr * 32 + mt * 16 + lg * 4 + v;
      #pragma unroll
      for (int nt = 0; nt < 2; ++nt) {
        int col = o0 + wc * 32 + nt * 16 + l15;
        outb[(size_t)row * EMBD + col] = f2bfu(tanhf(acc[mt][nt][v] + bv[nt]));
      }
    }
}

// K6pre v5: same LDS layout & output bytes as v4, but line-coalesced reads:
// idx = u*256+t -> row=idx>>5, c32=idx&31; 32 consecutive lanes cover one
// row's full 512B (4 fully-used cachelines/instr, merged). Grid 768 x 6,
// one barrier per block. Wt[grel][i][o][jc], chunk ch at ch^(o&7).
__global__ __launch_bounds__(256) void k_wt(const float* __restrict__ bilW,
                                            unsigned short* __restrict__ wt,
                                            int gbase) {
  __shared__ float Ls[64 * 128];
  const int grel = blockIdx.x >> 6;
  const int i = blockIdx.x & 63;
  const int oc = blockIdx.y;
  const int t = threadIdx.x;
  const size_t krow = (size_t)(gbase + grel) * 4096 + (size_t)i * 64;
  // stage: line-coalesced reads, XOR-swizzled chunk slots
  #pragma unroll
  for (int u = 0; u < 8; ++u) {
    const int idx = u * 256 + t;
    const int row = idx >> 5, c32 = idx & 31;
    f32x4 v = *(const f32x4*)&bilW[(krow + row) * 768 + oc * 128 + c32 * 4];
    *(f32x4*)&Ls[row * 128 + ((c32 ^ (row & 31)) * 4)] = v;
  }
  __syncthreads();
  // transpose out: thread owns (o2, chunks chb..chb+3)
  const int o2 = t >> 1, chb = (t & 1) * 4;
  const int og = oc * 128 + o2;
  const size_t outbase = (((size_t)grel * 64 + i) * 768 + og) * 64;
  #pragma unroll
  for (int u = 0; u < 4; ++u) {
    const int ch = chb + u;
    i32x4 pk;
    #pragma unroll
    for (int p = 0; p < 4; ++p) {
      const int j0 = ch * 8 + 2 * p;
      float v0 = Ls[j0 * 128 + (((o2 >> 2) ^ (j0 & 31)) * 4) + (o2 & 3)];
      const int j1 = j0 + 1;
      float v1 = Ls[j1 * 128 + (((o2 >> 2) ^ (j1 & 31)) * 4) + (o2 & 3)];
      pk[p] = (unsigned)f2bfu(v0) | ((unsigned)f2bfu(v1) << 16);
    }
    *(i32x4*)&wt[outbase + (size_t)(ch ^ (og & 7)) * 8] = pk;
  }
}

// K6: group bilinear via MFMA v3 (round-9 verified, 116us). BM=128, BN=128,
// 2x2 waves, wave 64x64. W from pre-transposed bf16 Wt (linear staging,
// swizzle pre-baked); A-tile generated cooperatively into LDS (XOR-swizzled);
// all frag reads at LDS bank floor. 1-D grid with XCD-aware decode.
__global__ __launch_bounds__(256, 2) void k_bil_mfma(
    const unsigned short* __restrict__ hsb,
    const unsigned short* __restrict__ tsb,
    const unsigned short* __restrict__ wt,
    float* __restrict__ part,
    int nslice, int gbase) {
  __shared__ __align__(16) unsigned short b1s[128][72];
  __shared__ __align__(16) unsigned short AsF[128 * 64];
  __shared__ __align__(16) unsigned short WsF[128 * 64];
  const int d = blockIdx.x;
  const int xcd = d & 7;
  const int q = d >> 3;
  const int r = q & 7;
  const int sl = q >> 3;
  const int s = xcd + 8 * sl;
  if (s >= nslice) return;
  const int oy = s % 6;
  const int z = s / 6;
  const int g = gbase + z;
  const int r0 = r * 128;
  const int o0 = oy * 128;

  const int t = threadIdx.x;
  const int lane = t & 63, wid = t >> 6;
  const int wr = wid >> 1, wc = wid & 1;
  const int l15 = lane & 15, lg = lane >> 4;
  const int rr = t >> 1, h = t & 1;   // gen mapping: thread owns (row rr, j-half h)

  // stage b1 slab (padded rows) + b2 into registers
  float b2f[32];
  #pragma unroll
  for (int u = 0; u < 4; ++u) {
    i32x4 hv = *(const i32x4*)&hsb[(size_t)(r0 + rr) * EMBD + g * 64 + h * 32 + u * 8];
    *(i32x4*)&b1s[rr][h * 32 + u * 8] = hv;
    i32x4 tv = *(const i32x4*)&tsb[(size_t)(r0 + rr) * EMBD + g * 64 + h * 32 + u * 8];
    const unsigned short* sp = (const unsigned short*)&tv;
    #pragma unroll
    for (int e = 0; e < 8; ++e) b2f[u * 8 + e] = bfu2f(sp[e]);
  }

  f32x4 acc[4][4];
  #pragma unroll
  for (int a = 0; a < 4; ++a)
    #pragma unroll
    for (int b = 0; b < 4; ++b) acc[a][b] = (f32x4){0.f, 0.f, 0.f, 0.f};

  for (int it = 0; it < 64; ++it) {
    __syncthreads();   // previous iteration's frag readers done (+ b1s ready at it=0)
    // W tile loads (bf16, pre-swizzled) -- issue early
    const size_t wbase = ((size_t)(z * 64 + it) * 768 + o0) * 64;
    i32x4 wv[4];
    #pragma unroll
    for (int u = 0; u < 4; ++u)
      wv[u] = *(const i32x4*)&wt[wbase + (size_t)u * 2048 + t * 8];
    // cooperative A-tile generation: As[rr][j] = bf16(b1[rr]*b2[rr][j])
    float b1 = bfu2f(b1s[rr][it]);
    #pragma unroll
    for (int u = 0; u < 4; ++u) {
      i32x4 a;
      #pragma unroll
      for (int p = 0; p < 4; ++p) {
        unsigned lo = f2bfu(b1 * b2f[u * 8 + 2 * p]);
        unsigned hi = f2bfu(b1 * b2f[u * 8 + 2 * p + 1]);
        a[p] = lo | (hi << 16);
      }
      int sc = (h * 4 + u) ^ (rr & 7);
      *(i32x4*)&AsF[rr * 64 + sc * 8] = a;
    }
    // W tile -> LDS, linear (swizzle baked into Wt)
    #pragma unroll
    for (int u = 0; u < 4; ++u)
      *(i32x4*)&WsF[u * 2048 + t * 8] = wv[u];
    __syncthreads();
    // fragments + MFMA
    #pragma unroll
    for (int ks = 0; ks < 2; ++ks) {
      U8 bfrg[4];
      #pragma unroll
      for (int nt = 0; nt < 4; ++nt) {
        int O = wc * 64 + nt * 16 + l15;
        bfrg[nt].iv = *(const i32x4*)&WsF[O * 64 + ((ks * 4 + lg) ^ (O & 7)) * 8];
      }
      #pragma unroll
      for (int mt = 0; mt < 4; ++mt) {
        int R = wr * 64 + mt * 16 + l15;
        U8 af;
        af.iv = *(const i32x4*)&AsF[R * 64 + ((ks * 4 + lg) ^ (R & 7)) * 8];
        #pragma unroll
        for (int nt = 0; nt < 4; ++nt)
          acc[mt][nt] = __builtin_amdgcn_mfma_f32_16x16x32_bf16(af.bv, bfrg[nt].bv, acc[mt][nt], 0, 0, 0);
      }
    }
  }
  float* pb = part + (size_t)g * NP * EMBD;
  #pragma unroll
  for (int mt = 0; mt < 4; ++mt)
    #pragma unroll
    for (int v = 0; v < 4; ++v) {
      int row = r0 + wr * 64 + mt * 16 + lg * 4 + v;
      #pragma unroll
      for (int nt = 0; nt < 4; ++nt) {
        int col = o0 + wc * 64 + nt * 16 + l15;
        pb[(size_t)row * EMBD + col] = acc[mt][nt][v];
      }
    }
}

// K7: rn = l2norm(r_emb_table @ re_W + re_b)
__global__ __launch_bounds__(256) void k_rel(const float* __restrict__ remb,
                                             const float* __restrict__ reW,
                                             const float* __restrict__ reb,
                                             float* __restrict__ rn) {
  int c = blockIdx.x;
  __shared__ float row_s[DD];
  int tid = threadIdx.x;
  for (int d = tid; d < DD; d += 256) row_s[d] = remb[(size_t)c * DD + d];
  __syncthreads();
  float v[3];
  float ss = 0.f;
  #pragma unroll
  for (int i = 0; i < 3; ++i) {
    int j = tid + i * 256;
    float acc = reb[j];
    for (int d = 0; d < DD; ++d) acc += row_s[d] * reW[(size_t)d * EMBD + j];
    v[i] = acc;
    ss += acc * acc;
  }
  float tot = blockReduceSum(ss);
  float scale = 1.f / fmaxf(sqrtf(tot), 1e-12f);
  #pragma unroll
  for (int i = 0; i < 3; ++i) rn[(size_t)c * EMBD + tid + i * 256] = v[i] * scale;
}

// K8 v3: fused partial-reduce + bias + l2norm + class dots.
// emb[r,:] = bilb + sum_z part[z][r][:]; logits[r,c] = l2norm(emb) . rn[c].
__global__ __launch_bounds__(128) void k_logits(const float* __restrict__ part,
                                                const float* __restrict__ bilb,
                                                const float* __restrict__ rn,
                                                float* __restrict__ out) {
  int r = blockIdx.x;
  __shared__ float row_s[EMBD];
  int tid = threadIdx.x;
  float ss = 0.f;
  #pragma unroll
  for (int i = 0; i < 6; ++i) {
    int d = tid + i * 128;
    float x = bilb[d];
    #pragma unroll
    for (int zz = 0; zz < 12; ++zz)
      x += part[(size_t)zz * NP * EMBD + (size_t)r * EMBD + d];
    row_s[d] = x;
    ss += x * x;
  }
  float tot = blockReduceSum(ss);
  float inv = 1.f / fmaxf(sqrtf(tot), 1e-12f);
  const int wv = tid >> 6, lane = tid & 63;
  const int gi = lane >> 3, sub = lane & 7;
  for (int pass = 0; pass < 7; ++pass) {
    int c = pass * 16 + wv * 8 + gi;
    float acc = 0.f;
    if (c < NCLS) {
      const float* rp = rn + (size_t)c * EMBD;
      #pragma unroll
      for (int k = 0; k < 96; ++k) acc += row_s[sub + k * 8] * rp[sub + k * 8];
    }
    acc += __shfl_xor(acc, 4, 64);
    acc += __shfl_xor(acc, 2, 64);
    acc += __shfl_xor(acc, 1, 64);
    if (c < NCLS && sub == 0) out[(size_t)r * NCLS + c] = acc * inv;
  }
}

extern "C" void kernel_launch(void* const* d_in, const int* in_sizes, int n_in,
                              void* d_out, int out_size, void* d_ws, size_t ws_size,
                              hipStream_t stream) {
  const float* seq   = (const float*)d_in[0];
  const float* att   = (const float*)d_in[1];
  const int*   midx  = (const int*)d_in[2];
  const unsigned char* mask = (const unsigned char*)d_in[3];
  const int*   pairs = (const int*)d_in[4];
  const float* headW = (const float*)d_in[5];
  const float* headb = (const float*)d_in[6];
  const float* tailW = (const float*)d_in[7];
  const float* tailb = (const float*)d_in[8];
  const float* bilW  = (const float*)d_in[9];
  const float* bilb  = (const float*)d_in[10];
  const float* remb  = (const float*)d_in[11];
  const float* reW   = (const float*)d_in[12];
  const float* reb   = (const float*)d_in[13];
  float* out = (float*)d_out;

  float* w = (float*)d_ws;
  float* e_emb = w;  w += (size_t)NN * EE * DD;
  float* cntv  = w;  w += NN * EE;
  int*   vbuf  = (int*)w; w += NN * EE;
  float* e_att = w;  w += (size_t)NN * EE * HH * CC;     // 6.29 MB
  float* ht    = w;  w += (size_t)NN * PP * CC;          // 4.19 MB
  float* xh    = w;  w += (size_t)NP * K2D;              // 6.29 MB
  float* xt    = w;  w += (size_t)NP * K2D;              // 6.29 MB
  float* embv  = w;  w += (size_t)NP * EMBD;             // kept for layout stability
  float* rn    = w;  w += (size_t)NCLS * EMBD;
  unsigned short* hsb = (unsigned short*)w;              // bf16 [1024][768]
  w += (size_t)NP * EMBD / 2;
  unsigned short* tsb = (unsigned short*)w;
  w += (size_t)NP * EMBD / 2;
  float* part = w;  w += (size_t)12 * NP * EMBD;         // 37.75 MB
  unsigned short* wt_big = (unsigned short*)w;
  size_t wt_bytes = (size_t)12 * 64 * 768 * 64 * 2;      // 75.5 MB
  size_t need_big = (size_t)((char*)wt_big - (char*)d_ws) + wt_bytes;
  (void)embv;

  k_entity<<<NN * EE, 256, 0, stream>>>(seq, midx, mask, e_emb, cntv, vbuf);
  k_eatt<<<NN * EE * HH, 256, 0, stream>>>(att, midx, cntv, vbuf, e_att);
  k_ht<<<NN * PP, 256, 0, stream>>>(e_att, pairs, ht);
  k_fill<<<NP, 256, 0, stream>>>(e_emb, pairs, xh, xt);
  dim3 g4(PP / 64, DD / 64, NN);
  k_rs_mfma<<<g4, 256, 0, stream>>>(ht, seq, xh, xt);
  dim3 g5(NP / 64, EMBD / 64, 2);
  k_tanh_mfma<<<g5, 256, 0, stream>>>(xh, xt, headW, tailW, headb, tailb, hsb, tsb);

  if (ws_size >= need_big) {
    // single prepass + single bilinear pass (72 slices x 8 row-blocks)
    dim3 gw(12 * 64, 6);
    k_wt<<<gw, 256, 0, stream>>>(bilW, wt_big, 0);
    k_bil_mfma<<<64 * 9, 256, 0, stream>>>(hsb, tsb, wt_big, part, 72, 0);
  } else {
    // 3 rounds of 4 groups; Wt (25.2 MB) aliases dead e_att..embv (26.2 MB)
    unsigned short* wt_small = (unsigned short*)e_att;
    for (int qr = 0; qr < 3; ++qr) {
      dim3 gw(4 * 64, 6);
      k_wt<<<gw, 256, 0, stream>>>(bilW, wt_small, qr * 4);
      k_bil_mfma<<<64 * 3, 256, 0, stream>>>(hsb, tsb, wt_small, part, 24, qr * 4);
    }
  }
  k_rel<<<NCLS, 256, 0, stream>>>(remb, reW, reb, rn);
  k_logits<<<NP, 128, 0, stream>>>(part, bilb, rn, out);
}